// Round 1
// baseline (127.443 us; speedup 1.0000x reference)
//
#include <hip/hip_runtime.h>

// BEV pooling: out[bin, c] = sum over points i with ranks_bev[i]==bin of
//                            depth_flat[ranks_depth[i]] * feat_flat[ranks_feat[i], c]
// ranks_bev is SORTED. Two phases:
//   1) seg[b] = lower_bound(rb, b) via vectorized boundary detection (int4)
//   2) ONE WAVE PER BIN, 16 point-slots x 4 channel-lanes. NEW in this round:
//      the point loop is a branchless, wave-uniform-trip-count, 2-stage rotated
//      software pipeline: value loads (depth + 5x float4 feat) for iteration
//      k+1 are issued BEFORE the FMAs of iteration k wait on their data, and
//      indices are prefetched 2 iterations ahead. Out-of-range slots clamp
//      their index to hi-1 and zero their weight, so over-prefetch is safe and
//      the loop has no divergent branches. This doubles per-wave memory-level
//      parallelism; the kernel was latency-bound (VALUBusy 26%, HBM 10%,
//      L2-resident inputs) with only ~8 loads in flight per wave.

#define CHN 80

__global__ __launch_bounds__(256)
void seg_starts_kernel(const int* __restrict__ rb, int* __restrict__ seg,
                       int P, int total_bev) {
    int q = blockIdx.x * blockDim.x + threadIdx.x;   // quad index
    int i4 = q * 4;
    if (i4 >= P) return;
    const int4 v = *reinterpret_cast<const int4*>(rb + i4);
    int prev = (i4 == 0) ? -1 : rb[i4 - 1];
    int cur;
    cur = v.x; for (int b = prev + 1; b <= cur; ++b) seg[b] = i4 + 0; prev = cur;
    cur = v.y; for (int b = prev + 1; b <= cur; ++b) seg[b] = i4 + 1; prev = cur;
    cur = v.z; for (int b = prev + 1; b <= cur; ++b) seg[b] = i4 + 2; prev = cur;
    cur = v.w; for (int b = prev + 1; b <= cur; ++b) seg[b] = i4 + 3; prev = cur;
    if (i4 + 4 >= P) {
        for (int b = prev + 1; b <= total_bev; ++b) seg[b] = P;
    }
}

// 4 waves/EU min -> VGPR cap 128; the pipeline needs ~2x21 value regs + 20 acc.
__global__ __launch_bounds__(256, 4)
void bev_pool_kernel(const float* __restrict__ depth,
                     const float* __restrict__ feat,
                     const int* __restrict__ rd,
                     const int* __restrict__ rf,
                     const int* __restrict__ seg,
                     float* __restrict__ out,
                     int total_bev) {
    const int wave = threadIdx.x >> 6;               // 4 waves per block
    const int lane = threadIdx.x & 63;
    const int bin = blockIdx.x * 4 + wave;
    if (bin >= total_bev) return;

    const int slot = lane >> 2;                      // 0..15 point slot
    const int ll   = lane & 3;                       // 0..3 channel sub-lane

    const int lo = seg[bin];                         // wave-uniform -> s_load
    const int hi = seg[bin + 1];

    float4 a0 = make_float4(0.f, 0.f, 0.f, 0.f);
    float4 a1 = a0, a2 = a0, a3 = a0, a4 = a0;

    if (hi > lo) {
        const int n_iter = (hi - lo + 15) >> 4;      // wave-uniform trip count
        const int last   = hi - 1;                   // clamp target (>= lo >= 0)
        const int base   = lo + slot;                // this lane's point stream

        // Clamped index fetch for virtual iteration K (safe to over-prefetch:
        // out-of-range lanes re-read point `last`, whose weight is masked to 0).
        #define LDIDX(K, DI, FI) do {                                          \
            int i_  = base + ((K) << 4);                                       \
            int ix_ = i_ < last ? i_ : last;                                   \
            DI = rd[ix_]; FI = rf[ix_];                                        \
        } while (0)

        #define LDVAL(DI, FI, D, F0, F1, F2, F3, F4) do {                      \
            D = depth[DI];                                                     \
            const float4* fr_ =                                                \
                reinterpret_cast<const float4*>(feat + (size_t)(FI) * CHN) + ll;\
            F0 = fr_[0]; F1 = fr_[4]; F2 = fr_[8]; F3 = fr_[12]; F4 = fr_[16]; \
        } while (0)

        #define FMA5(K, D, F0, F1, F2, F3, F4) do {                            \
            const float w_ = (base + ((K) << 4) < hi) ? (D) : 0.f;             \
            a0.x += w_*F0.x; a0.y += w_*F0.y; a0.z += w_*F0.z; a0.w += w_*F0.w;\
            a1.x += w_*F1.x; a1.y += w_*F1.y; a1.z += w_*F1.z; a1.w += w_*F1.w;\
            a2.x += w_*F2.x; a2.y += w_*F2.y; a2.z += w_*F2.z; a2.w += w_*F2.w;\
            a3.x += w_*F3.x; a3.y += w_*F3.y; a3.z += w_*F3.z; a3.w += w_*F3.w;\
            a4.x += w_*F4.x; a4.y += w_*F4.y; a4.z += w_*F4.z; a4.w += w_*F4.w;\
        } while (0)

        int diA, fiA, diB, fiB, diC, fiC;
        float dA; float4 fA0, fA1, fA2, fA3, fA4;
        float dB; float4 fB0, fB1, fB2, fB3, fB4;

        // Prologue: values for iter 0 in A; indices for iters 1 and 2 staged.
        LDIDX(0, diA, fiA);
        LDIDX(1, diB, fiB);
        LDIDX(2, diC, fiC);
        LDVAL(diA, fiA, dA, fA0, fA1, fA2, fA3, fA4);

        // Rotated 2-stage pipeline. Loop invariant at entry of round k:
        //   valA = values(k), idxB = indices(k+1), idxC = indices(k+2).
        // Odd n_iter: the final (k+1) stage runs fully masked — harmless.
        for (int k = 0; k < n_iter; k += 2) {
            LDVAL(diB, fiB, dB, fB0, fB1, fB2, fB3, fB4);   // issue values k+1
            LDIDX(k + 3, diB, fiB);                         // issue idx   k+3
            FMA5(k, dA, fA0, fA1, fA2, fA3, fA4);           // compute k (waits A)
            LDVAL(diC, fiC, dA, fA0, fA1, fA2, fA3, fA4);   // issue values k+2
            LDIDX(k + 4, diC, fiC);                         // issue idx   k+4
            FMA5(k + 1, dB, fB0, fB1, fB2, fB3, fB4);       // compute k+1 (waits B)
        }

        #undef LDIDX
        #undef LDVAL
        #undef FMA5
    }

    // Butterfly reduce across the 16 slots (lane bits 2..5). XOR butterfly is
    // self-symmetric, so in-place += is correct at every level.
    #pragma unroll
    for (int ofs = 4; ofs <= 32; ofs <<= 1) {
        a0.x += __shfl_xor(a0.x, ofs, 64); a0.y += __shfl_xor(a0.y, ofs, 64);
        a0.z += __shfl_xor(a0.z, ofs, 64); a0.w += __shfl_xor(a0.w, ofs, 64);
        a1.x += __shfl_xor(a1.x, ofs, 64); a1.y += __shfl_xor(a1.y, ofs, 64);
        a1.z += __shfl_xor(a1.z, ofs, 64); a1.w += __shfl_xor(a1.w, ofs, 64);
        a2.x += __shfl_xor(a2.x, ofs, 64); a2.y += __shfl_xor(a2.y, ofs, 64);
        a2.z += __shfl_xor(a2.z, ofs, 64); a2.w += __shfl_xor(a2.w, ofs, 64);
        a3.x += __shfl_xor(a3.x, ofs, 64); a3.y += __shfl_xor(a3.y, ofs, 64);
        a3.z += __shfl_xor(a3.z, ofs, 64); a3.w += __shfl_xor(a3.w, ofs, 64);
        a4.x += __shfl_xor(a4.x, ofs, 64); a4.y += __shfl_xor(a4.y, ofs, 64);
        a4.z += __shfl_xor(a4.z, ofs, 64); a4.w += __shfl_xor(a4.w, ofs, 64);
    }

    // Lane L (< 20) stores chunk L = j*4 + ll with j = L>>2  ->  its a[j].
    if (lane < 20) {
        const int j = lane >> 2;
        float4 w = a0;
        if (j == 1) w = a1;
        else if (j == 2) w = a2;
        else if (j == 3) w = a3;
        else if (j == 4) w = a4;
        *reinterpret_cast<float4*>(out + (size_t)bin * CHN + lane * 4) = w;
    }
}

extern "C" void kernel_launch(void* const* d_in, const int* in_sizes, int n_in,
                              void* d_out, int out_size, void* d_ws, size_t ws_size,
                              hipStream_t stream) {
    const float* depth = (const float*)d_in[0];
    const float* feat  = (const float*)d_in[1];
    const int*   rd    = (const int*)d_in[2];
    const int*   rf    = (const int*)d_in[3];
    const int*   rb    = (const int*)d_in[4];
    // d_in[5], d_in[6] (interval_starts/lengths) unused per reference; d_in[7] scalar total_bev.
    float* out = (float*)d_out;

    const int P = in_sizes[2];
    const int total_bev = out_size / CHN;   // 40000

    int* seg = (int*)d_ws;                  // total_bev+1 ints, rewritten fully every call

    const int quads = (P + 3) / 4;
    seg_starts_kernel<<<(quads + 255) / 256, 256, 0, stream>>>(rb, seg, P, total_bev);
    bev_pool_kernel<<<(total_bev + 3) / 4, 256, 0, stream>>>(depth, feat, rd, rf, seg,
                                                             out, total_bev);
}

// Round 3
// 114.610 us; speedup vs baseline: 1.1120x; 1.1120x over previous
//
#include <hip/hip_runtime.h>

// BEV pooling: out[bin, c] = sum over points i with ranks_bev[i]==bin of
//                            depth_flat[ranks_depth[i]] * feat_flat[ranks_feat[i], c]
// ranks_bev is SORTED. Two phases:
//   1) seg[b] = lower_bound(rb, b) via vectorized boundary detection (int4)
//   2) ONE WAVE PER BIN, 16 point-slots x 4 channel-lanes; round-0 loop
//      (early-exit, one-ahead index prefetch) — the R1 branchless pipeline
//      regressed (compiler wouldn't hold value stages: VGPR stayed 40).
//      Epilogue is an LDS transpose-reduce instead of the 80-swizzle
//      butterfly. Per bin: 5 ds_write_b128 + 8 ds_read_b128 (two 20-lane
//      groups summing 8 slots each) + 7 float4 adds + one shfl_xor(32),
//      vs 80 ds_swizzle + 80 wave-wide adds. Cuts the shared LDS-pipe and
//      VALU demand of the epilogue ~3x. Per-wave-private LDS -> no barrier.
// (R2 bench was an infra failure — container died twice, kernel never ran.
//  Audited for hang/fault hazards: none found. Resubmitting unchanged.)

#define CHN 80
#define SSTRIDE 84   // floats per slot row in LDS: 80 + 4 pad (bank spread, 16B-aligned)

__global__ __launch_bounds__(256)
void seg_starts_kernel(const int* __restrict__ rb, int* __restrict__ seg,
                       int P, int total_bev) {
    int q = blockIdx.x * blockDim.x + threadIdx.x;   // quad index
    int i4 = q * 4;
    if (i4 >= P) return;
    const int4 v = *reinterpret_cast<const int4*>(rb + i4);
    int prev = (i4 == 0) ? -1 : rb[i4 - 1];
    int cur;
    cur = v.x; for (int b = prev + 1; b <= cur; ++b) seg[b] = i4 + 0; prev = cur;
    cur = v.y; for (int b = prev + 1; b <= cur; ++b) seg[b] = i4 + 1; prev = cur;
    cur = v.z; for (int b = prev + 1; b <= cur; ++b) seg[b] = i4 + 2; prev = cur;
    cur = v.w; for (int b = prev + 1; b <= cur; ++b) seg[b] = i4 + 3; prev = cur;
    if (i4 + 4 >= P) {
        for (int b = prev + 1; b <= total_bev; ++b) seg[b] = P;
    }
}

__global__ __launch_bounds__(256)
void bev_pool_kernel(const float* __restrict__ depth,
                     const float* __restrict__ feat,
                     const int* __restrict__ rd,
                     const int* __restrict__ rf,
                     const int* __restrict__ seg,
                     float* __restrict__ out,
                     int total_bev) {
    __shared__ float lds_buf[4][16 * SSTRIDE];       // per-wave-private 16x84 floats

    const int wave = threadIdx.x >> 6;               // 4 waves per block
    const int lane = threadIdx.x & 63;
    const int bin = blockIdx.x * 4 + wave;
    if (bin >= total_bev) return;

    const int slot = lane >> 2;                      // 0..15 point slot
    const int ll   = lane & 3;                       // 0..3 channel sub-lane

    const int lo = seg[bin];
    const int hi = seg[bin + 1];

    float4 a0 = make_float4(0.f, 0.f, 0.f, 0.f);
    float4 a1 = a0, a2 = a0, a3 = a0, a4 = a0;

    // One-ahead index prefetch; rd/rf for a wave-iter are one 64B line.
    int i = lo + slot;
    bool valid = i < hi;
    int di = 0, fi = 0;
    if (valid) { di = rd[i]; fi = rf[i]; }
    while (valid) {
        const int ni = i + 16;
        const bool nvalid = ni < hi;
        int ndi = 0, nfi = 0;
        if (nvalid) { ndi = rd[ni]; nfi = rf[ni]; }

        const float d = depth[di];
        const float4* frow = reinterpret_cast<const float4*>(feat + (size_t)fi * CHN) + ll;
        const float4 f0 = frow[0];     // chunk ll      (floats  ll*4 .. ll*4+3)
        const float4 f1 = frow[4];     // chunk ll+4
        const float4 f2 = frow[8];
        const float4 f3 = frow[12];
        const float4 f4 = frow[16];
        a0.x += d * f0.x; a0.y += d * f0.y; a0.z += d * f0.z; a0.w += d * f0.w;
        a1.x += d * f1.x; a1.y += d * f1.y; a1.z += d * f1.z; a1.w += d * f1.w;
        a2.x += d * f2.x; a2.y += d * f2.y; a2.z += d * f2.z; a2.w += d * f2.w;
        a3.x += d * f3.x; a3.y += d * f3.y; a3.z += d * f3.z; a3.w += d * f3.w;
        a4.x += d * f4.x; a4.y += d * f4.y; a4.z += d * f4.z; a4.w += d * f4.w;

        i = ni; di = ndi; fi = nfi; valid = nvalid;
    }

    // ---- Epilogue: LDS transpose-reduce (replaces 80-swizzle butterfly) ----
    // Write: lane (slot,ll) owns chunks {4j+ll}; chunk k lives at float offset
    // slot*SSTRIDE + 4k. All offsets 16B-aligned (SSTRIDE*4B = 336 = 16*21).
    {
        float* wb = &lds_buf[wave][slot * SSTRIDE + 4 * ll];
        *reinterpret_cast<float4*>(wb +  0) = a0;    // chunk ll
        *reinterpret_cast<float4*>(wb + 16) = a1;    // chunk ll+4
        *reinterpret_cast<float4*>(wb + 32) = a2;    // chunk ll+8
        *reinterpret_cast<float4*>(wb + 48) = a3;    // chunk ll+12
        *reinterpret_cast<float4*>(wb + 64) = a4;    // chunk ll+16
    }
    // Read: group g = lane>>5 sums slots g*8..g*8+7 of chunk c = lane&31
    // (active only for c < 20). Same-wave RAW: LDS ops retire in program
    // order within a wave and the compiler inserts the lgkmcnt wait;
    // region is wave-private so no __syncthreads needed.
    const int g = lane >> 5;
    const int c = lane & 31;
    float4 r = make_float4(0.f, 0.f, 0.f, 0.f);
    if (c < 20) {
        const float* rp = &lds_buf[wave][g * 8 * SSTRIDE + c * 4];
        #pragma unroll
        for (int t = 0; t < 8; ++t) {
            const float4 v = *reinterpret_cast<const float4*>(rp + t * SSTRIDE);
            r.x += v.x; r.y += v.y; r.z += v.z; r.w += v.w;
        }
    }
    // Merge the two slot-halves: lanes 0..19 get lanes 32..51's partial.
    // Must run at top level (both groups active in the shfl).
    r.x += __shfl_xor(r.x, 32, 64);
    r.y += __shfl_xor(r.y, 32, 64);
    r.z += __shfl_xor(r.z, 32, 64);
    r.w += __shfl_xor(r.w, 32, 64);

    if (lane < 20) {
        *reinterpret_cast<float4*>(out + (size_t)bin * CHN + lane * 4) = r;
    }
}

extern "C" void kernel_launch(void* const* d_in, const int* in_sizes, int n_in,
                              void* d_out, int out_size, void* d_ws, size_t ws_size,
                              hipStream_t stream) {
    const float* depth = (const float*)d_in[0];
    const float* feat  = (const float*)d_in[1];
    const int*   rd    = (const int*)d_in[2];
    const int*   rf    = (const int*)d_in[3];
    const int*   rb    = (const int*)d_in[4];
    // d_in[5], d_in[6] (interval_starts/lengths) unused per reference; d_in[7] scalar total_bev.
    float* out = (float*)d_out;

    const int P = in_sizes[2];
    const int total_bev = out_size / CHN;   // 40000

    int* seg = (int*)d_ws;                  // total_bev+1 ints, rewritten fully every call

    const int quads = (P + 3) / 4;
    seg_starts_kernel<<<(quads + 255) / 256, 256, 0, stream>>>(rb, seg, P, total_bev);
    bev_pool_kernel<<<(total_bev + 3) / 4, 256, 0, stream>>>(depth, feat, rd, rf, seg,
                                                             out, total_bev);
}